// Round 1
// baseline (676.639 us; speedup 1.0000x reference)
//
#include <hip/hip_runtime.h>
#include <math.h>

#define EPS 1e-8f
#define RAD2DEG 57.29577951308232f

// 16 lanes cooperate on one row of data[N,64]. Each lane owns a float4 slice
// (16B coalesced) and a private 4x3 fragment of W. Segmented shuffle-reduce
// (width 16) produces pred[3] on lane 0, which runs the epilogue.
__global__ __launch_bounds__(256) void cos_loss_kernel(
    const float* __restrict__ data,   // [N, 64]
    const float* __restrict__ lab,    // [N, 3]
    const float* __restrict__ W,      // [64, 3] row-major
    const float* __restrict__ b,      // [3]
    float* __restrict__ out,          // [N]
    int N)
{
    const int lane  = threadIdx.x & 15;   // position within the 16-lane row group
    const int group = threadIdx.x >> 4;   // row group within block (0..15)

    // Preload this lane's W fragment: rows lane*4 .. lane*4+3, all 3 cols.
    float w[4][3];
#pragma unroll
    for (int j = 0; j < 4; ++j)
#pragma unroll
        for (int c = 0; c < 3; ++c)
            w[j][c] = W[(lane * 4 + j) * 3 + c];
    const float b0 = b[0], b1 = b[1], b2 = b[2];

    const int groups_per_block = blockDim.x >> 4;                 // 16
    const long long stride = (long long)gridDim.x * groups_per_block;

    for (long long row = (long long)blockIdx.x * groups_per_block + group;
         row < N; row += stride) {

        // Coalesced: 16 consecutive lanes read 16 consecutive float4s = one row.
        const float4 v = *(const float4*)(data + row * 64 + lane * 4);

        float p0 = v.x * w[0][0] + v.y * w[1][0] + v.z * w[2][0] + v.w * w[3][0];
        float p1 = v.x * w[0][1] + v.y * w[1][1] + v.z * w[2][1] + v.w * w[3][1];
        float p2 = v.x * w[0][2] + v.y * w[1][2] + v.z * w[2][2] + v.w * w[3][2];

        // Segmented reduction across the 16 lanes of this row group.
#pragma unroll
        for (int off = 8; off > 0; off >>= 1) {
            p0 += __shfl_down(p0, off, 16);
            p1 += __shfl_down(p1, off, 16);
            p2 += __shfl_down(p2, off, 16);
        }

        if (lane == 0) {
            p0 += b0; p1 += b1; p2 += b2;

            // F.normalize(pred, dim=1): x / max(||x||, eps)
            float norm = sqrtf(p0 * p0 + p1 * p1 + p2 * p2);
            float inv  = 1.0f / fmaxf(norm, EPS);
            float q0 = p0 * inv, q1 = p1 * inv, q2 = p2 * inv;

            float l0 = lab[row * 3 + 0];
            float l1 = lab[row * 3 + 1];
            float l2 = lab[row * 3 + 2];

            float dot = q0 * l0 + q1 * l1 + q2 * l2;
            float na  = fmaxf(sqrtf(q0 * q0 + q1 * q1 + q2 * q2), EPS);
            float nb  = fmaxf(sqrtf(l0 * l0 + l1 * l1 + l2 * l2), EPS);

            float cosv = dot / (na * nb);
            // Clamp: acos has infinite slope at +/-1; a 1-ulp overshoot would
            // give NaN -> 0 vs ref's ~180 deg (the dataset HAS such a sample:
            // stub absmax was exactly 180). Clamping keeps us within ~0.05 deg
            // of the true angle at the cliff.
            cosv = fminf(1.0f, fmaxf(-1.0f, cosv));

            float ang = acosf(cosv) * RAD2DEG;
            if (isnan(ang)) ang = 0.0f;   // belt-and-suspenders; unreachable after clamp
            out[row] = ang;
        }
    }
}

extern "C" void kernel_launch(void* const* d_in, const int* in_sizes, int n_in,
                              void* d_out, int out_size, void* d_ws, size_t ws_size,
                              hipStream_t stream) {
    const float* data = (const float*)d_in[0];   // [N, 64]
    const float* lab  = (const float*)d_in[1];   // [N, 3]
    const float* W    = (const float*)d_in[2];   // [64, 3]
    const float* b    = (const float*)d_in[3];   // [3]
    float* out        = (float*)d_out;           // [N]

    const int N = in_sizes[0] / 64;

    const int block = 256;                       // 16 row-groups per block
    const int rows_per_block = block / 16;
    long long need = ((long long)N + rows_per_block - 1) / rows_per_block;
    int grid = (int)(need < 8192 ? need : 8192); // grid-stride beyond this
    if (grid < 1) grid = 1;

    cos_loss_kernel<<<grid, block, 0, stream>>>(data, lab, W, b, out, N);
}

// Round 2
// 671.592 us; speedup vs baseline: 1.0075x; 1.0075x over previous
//
#include <hip/hip_runtime.h>
#include <math.h>

#define EPS 1e-8f
#define RAD2DEG 57.29577951308232f
#define TILE 256   // rows per block

// Phase 1 (dot): 16-lane groups compute pred[3] per row via float4 loads +
// width-16 shuffle reduce; lane 0 stashes pred into LDS (no divergent math).
// Phase 2 (epilogue): after one barrier, all 256 threads run the
// normalize/cos/acos epilogue at full lane efficiency, 1 row/thread, with
// coalesced lab reads and coalesced out stores.
__global__ __launch_bounds__(256) void cos_loss_kernel(
    const float* __restrict__ data,   // [N, 64]
    const float* __restrict__ lab,    // [N, 3]
    const float* __restrict__ W,      // [64, 3] row-major
    const float* __restrict__ b,      // [3]
    float* __restrict__ out,          // [N]
    int N)
{
    __shared__ float4 pred_s[TILE];   // xyz = pred, w unused; stride 4 words -> clean banks

    const int tid   = threadIdx.x;
    const int lane  = tid & 15;       // position within 16-lane row group
    const int group = tid >> 4;       // row group 0..15

    // Per-lane W fragment: rows lane*4..lane*4+3, 3 cols (12 regs).
    float w[4][3];
#pragma unroll
    for (int j = 0; j < 4; ++j)
#pragma unroll
        for (int c = 0; c < 3; ++c)
            w[j][c] = W[(lane * 4 + j) * 3 + c];

    const int tileBase = blockIdx.x * TILE;
    const bool full = (tileBase + TILE <= N);   // only last block is partial

    // ---- Phase 1: 16 steps, each step the block covers 16 consecutive rows
    // (4 KB contiguous across the block's 4 waves). ----
#pragma unroll 4
    for (int j = 0; j < 16; ++j) {
        const int rlocal = j * 16 + group;
        const int row    = tileBase + rlocal;

        float4 v = make_float4(0.f, 0.f, 0.f, 0.f);
        if (full || row < N)
            v = *(const float4*)(data + (size_t)row * 64 + lane * 4);

        float p0 = v.x * w[0][0] + v.y * w[1][0] + v.z * w[2][0] + v.w * w[3][0];
        float p1 = v.x * w[0][1] + v.y * w[1][1] + v.z * w[2][1] + v.w * w[3][1];
        float p2 = v.x * w[0][2] + v.y * w[1][2] + v.z * w[2][2] + v.w * w[3][2];

#pragma unroll
        for (int off = 8; off > 0; off >>= 1) {
            p0 += __shfl_down(p0, off, 16);
            p1 += __shfl_down(p1, off, 16);
            p2 += __shfl_down(p2, off, 16);
        }

        if (lane == 0)
            pred_s[rlocal] = make_float4(p0, p1, p2, 0.f);  // single ds_write_b128
    }

    __syncthreads();

    // ---- Phase 2: full-width epilogue, 1 row/thread. ----
    const int row = tileBase + tid;
    if (row < N) {
        const float4 p = pred_s[tid];
        float p0 = p.x + b[0];
        float p1 = p.y + b[1];
        float p2 = p.z + b[2];

        // F.normalize(pred, dim=1)
        float norm = sqrtf(p0 * p0 + p1 * p1 + p2 * p2);
        float inv  = 1.0f / fmaxf(norm, EPS);
        float q0 = p0 * inv, q1 = p1 * inv, q2 = p2 * inv;

        // Coalesced: thread t reads 12 consecutive bytes at lab + row*12.
        const float l0 = lab[row * 3 + 0];
        const float l1 = lab[row * 3 + 1];
        const float l2 = lab[row * 3 + 2];

        float dot = q0 * l0 + q1 * l1 + q2 * l2;
        float na  = fmaxf(sqrtf(q0 * q0 + q1 * q1 + q2 * q2), EPS);
        float nb  = fmaxf(sqrtf(l0 * l0 + l1 * l1 + l2 * l2), EPS);

        float cosv = dot / (na * nb);
        // acos has infinite slope at +/-1; 1-ulp overshoot -> NaN -> 0 vs
        // ref's 180 deg (dataset contains such a sample). Clamp keeps us
        // within ~0.05 deg at the cliff.
        cosv = fminf(1.0f, fmaxf(-1.0f, cosv));

        float ang = acosf(cosv) * RAD2DEG;
        if (isnan(ang)) ang = 0.0f;   // unreachable after clamp, kept for safety
        out[row] = ang;
    }
}

extern "C" void kernel_launch(void* const* d_in, const int* in_sizes, int n_in,
                              void* d_out, int out_size, void* d_ws, size_t ws_size,
                              hipStream_t stream) {
    const float* data = (const float*)d_in[0];   // [N, 64]
    const float* lab  = (const float*)d_in[1];   // [N, 3]
    const float* W    = (const float*)d_in[2];   // [64, 3]
    const float* b    = (const float*)d_in[3];   // [3]
    float* out        = (float*)d_out;           // [N]

    const int N = in_sizes[0] / 64;

    const int grid = (N + TILE - 1) / TILE;      // 7813 blocks @ N=2M, ~30/CU
    cos_loss_kernel<<<grid, 256, 0, stream>>>(data, lab, W, b, out, N);
}